// Round 6
// baseline (5774.874 us; speedup 1.0000x reference)
//
#include <hip/hip_runtime.h>
#include <hip/hip_bf16.h>

#define DIN 49
#define HIN 32
#define WIN 64
#define CIN 32
#define DOUT 193
#define HOUT 256
#define WOUT 512
#define NPIX (HOUT * WOUT)      // 131072
#define NUPS (DOUT * NPIX)      // 25296896
#define NCONV (DIN * HIN * WIN) // 100352
#define DSPLIT 64
#define NZ 4 // 3 full z-slices of 64 + 1-plane tail (d=192)

// LGA LDS geometry: d-contiguous per pixel.
#define ROWS 20      // h halo rows
#define ROWSTRIDE 33 // pixel-row stride in pixels
#define PIXSTRIDE 12 // words per pixel (10 planes + 2 pad; 48 B, 16B-aligned)
#define NJOBS 800    // 10 planes * 20 rows * 4 segs
#define SUWORDS 7920

// ---------------------------------------------------------------------------
// Kernel 1: 3x3x3 conv, 32 -> 1 channels, zero pad 1, fp32 accumulate.
// ---------------------------------------------------------------------------
__global__ void conv3d_kernel(const float* __restrict__ x,
                              const float* __restrict__ w,
                              float* __restrict__ c) {
    __shared__ float ws[CIN * 27];
    for (int t = threadIdx.x; t < CIN * 27; t += blockDim.x)
        ws[t] = w[t];
    __syncthreads();

    int idx = blockIdx.x * blockDim.x + threadIdx.x;
    if (idx >= NCONV) return;
    int wq = idx % WIN;
    int t2 = idx / WIN;
    int hq = t2 % HIN;
    int dq = t2 / HIN;

    float acc = 0.f;
    for (int ci = 0; ci < CIN; ++ci) {
        const float* xb = x + ci * NCONV;
        const float* wb = ws + ci * 27;
#pragma unroll
        for (int kd = 0; kd < 3; ++kd) {
            int zd = dq + kd - 1;
            if (zd < 0 || zd >= DIN) continue;
#pragma unroll
            for (int kh = 0; kh < 3; ++kh) {
                int zh = hq + kh - 1;
                if (zh < 0 || zh >= HIN) continue;
#pragma unroll
                for (int kw = 0; kw < 3; ++kw) {
                    int zw = wq + kw - 1;
                    if (zw < 0 || zw >= WIN) continue;
                    acc += xb[(zd * HIN + zh) * WIN + zw] *
                           wb[(kd * 3 + kh) * 3 + kw];
                }
            }
        }
    }
    c[idx] = acc;
}

// ---------------------------------------------------------------------------
// Kernel 2: trilinear upsample, 8 outputs/thread along w, uint4 stores.
// ---------------------------------------------------------------------------
__global__ void upsample_kernel(const float* __restrict__ c,
                                __hip_bfloat16* __restrict__ u) {
    int t = blockIdx.x * blockDim.x + threadIdx.x;
    int wc = t & 63;
    int rest = t >> 6;
    int hh = rest & 255;
    int dd = rest >> 8;
    if (dd >= DOUT) return;

    float fd = (dd + 0.5f) * (49.0f / 193.0f) - 0.5f;
    fd = fminf(fmaxf(fd, 0.f), (float)(DIN - 1));
    int d0 = min((int)fd, DIN - 2);
    float ad = fd - (float)d0;

    float fh = (hh + 0.5f) * 0.125f - 0.5f;
    fh = fminf(fmaxf(fh, 0.f), (float)(HIN - 1));
    int h0 = min((int)fh, HIN - 2);
    float ah = fh - (float)h0;

    int cm1 = max(wc - 1, 0);
    int cp1 = min(wc + 1, WIN - 1);
    const float* p00 = c + (d0 * HIN + h0) * WIN;
    const float* p01 = p00 + WIN;
    const float* p10 = p00 + HIN * WIN;
    const float* p11 = p10 + WIN;

    float a[3];
    {
        float q00, q01, q10, q11;
        q00 = p00[cm1]; q01 = p01[cm1]; q10 = p10[cm1]; q11 = p11[cm1];
        a[0] = (q00 + ah * (q01 - q00)) * (1.f - ad) +
               (q10 + ah * (q11 - q10)) * ad;
        q00 = p00[wc]; q01 = p01[wc]; q10 = p10[wc]; q11 = p11[wc];
        a[1] = (q00 + ah * (q01 - q00)) * (1.f - ad) +
               (q10 + ah * (q11 - q10)) * ad;
        q00 = p00[cp1]; q01 = p01[cp1]; q10 = p10[cp1]; q11 = p11[cp1];
        a[2] = (q00 + ah * (q01 - q00)) * (1.f - ad) +
               (q10 + ah * (q11 - q10)) * ad;
    }

    union {
        unsigned short us[8];
        uint4 v4;
    } pk;
#pragma unroll
    for (int i = 0; i < 8; ++i) {
        float fw = (float)(wc * 8 + i) * 0.125f + (0.0625f - 0.5f);
        fw = fminf(fmaxf(fw, 0.f), (float)(WIN - 1));
        int w0 = min((int)fw, WIN - 2);
        float aw = fw - (float)w0;
        int idx = w0 - (wc - 1);
        float lo = (idx == 0) ? a[0] : a[1];
        float hi = (idx == 0) ? a[1] : a[2];
        float v = lo + aw * (hi - lo);
        __hip_bfloat16 b = __float2bfloat16(v);
        unsigned short usv;
        __builtin_memcpy(&usv, &b, 2);
        pk.us[i] = usv;
    }
    *((uint4*)(u + (size_t)dd * NPIX + hh * WOUT + wc * 8)) = pk.v4;
}

// ---------------------------------------------------------------------------
// LGA: 16x16 pixel tile x DSPLIT d-planes per block. d-contiguous LDS, wide
// ds_reads, coalesced 16B staging (loads issued just before the barrier so
// latency overlaps it; dat NOT live across compute -> low VGPR), bf16-packed
// guidance. amdgpu_waves_per_eu(4) pins VGPR <= 128 for 4 waves/SIMD.
// MODE 0: write volume (bf16). MODE 1: per-z online softmin partials.
// ---------------------------------------------------------------------------
__device__ __forceinline__ unsigned short bf16bits(float f) {
    __hip_bfloat16 h = __float2bfloat16(f);
    unsigned short b;
    __builtin_memcpy(&b, &h, 2);
    return b;
}

template <int MODE>
__global__ __launch_bounds__(256)
__attribute__((amdgpu_waves_per_eu(4))) void lga_kernel(
    const __hip_bfloat16* __restrict__ xin,
    const float* __restrict__ lg1,
    __hip_bfloat16* __restrict__ yout,
    float* __restrict__ part) {
    const int tid = threadIdx.x;
    const int tx = tid & 15;
    const int ty = tid >> 4;
    const int w0p = blockIdx.x * 16;
    const int h0p = blockIdx.y * 16;
    const int zb = blockIdx.z * DSPLIT;
    const int dend = min(zb + DSPLIT, DOUT);
    const int pix = (h0p + ty) * WOUT + (w0p + tx);
    const unsigned short* xus = (const unsigned short*)xin;

    __shared__ __align__(16) float su[SUWORDS];

    // ---- staging job decode (once): j = dl*80 + r*4 + seg (seg fastest) ----
    // k = 0..2 always active; k = 3 active iff tid < 32 (NJOBS = 800).
    int jb_lds[4], jb_row[4], jb_dl[4];
    bool jb_inb[4]; // spatial in-bounds (gh, gw)
#pragma unroll
    for (int k = 0; k < 4; ++k) {
        int j = tid + k * 256;
        int jj = (k == 3 && tid >= 32) ? 0 : j;
        int seg = jj & 3;
        int rowjob = jj >> 2; // dl*20 + r
        int r = rowjob % ROWS;
        int dl = rowjob / ROWS;
        int gh = h0p - 2 + r;
        int gwb = w0p - 8 + seg * 8; // 8-aligned -> 16B-aligned byte addr
        jb_dl[k] = dl;
        jb_lds[k] = (r * ROWSTRIDE + seg * 8) * PIXSTRIDE + dl;
        jb_row[k] = gh * WOUT + gwb;
        jb_inb[k] = gh >= 0 && gh < HOUT && gwb >= 0 && (gwb + 8) <= WOUT;
    }
    const bool k3act = (tid < 32);

    // ---- guidance: two passes over lg1 to keep register pressure low ----
    float asum = 0.f;
#pragma unroll
    for (int ch = 0; ch < 75; ++ch) asum += fabsf(lg1[ch * NPIX + pix]);
    float inv = 1.f / fmaxf(asum, 1e-12f);
    unsigned gp[39]; // 3 sections x 13 bf16-pairs
#pragma unroll
    for (int s = 0; s < 3; ++s)
#pragma unroll
        for (int p = 0; p < 13; ++p) {
            int c0 = s * 25 + 2 * p;
            float w0 = lg1[c0 * NPIX + pix] * inv;
            float w1 = (2 * p + 1 < 25) ? lg1[(c0 + 1) * NPIX + pix] * inv : 0.f;
            gp[s * 13 + p] =
                (unsigned)bf16bits(w0) | ((unsigned)bf16bits(w1) << 16);
        }

    const int pbase = (ty * ROWSTRIDE + tx + 6) * PIXSTRIDE;

    float m = -1e30f, l = 0.f, s_acc = 0.f; // MODE 1 online-softmin state

    for (int d0 = zb; d0 < dend; d0 += 8) {
        // Issue staging loads BEFORE the barrier: latency overlaps barrier
        // wait; dat live only through write_lds (keeps VGPR low).
        uint4 dat[4];
#pragma unroll
        for (int k = 0; k < 4; ++k) {
            int gd = d0 - 1 + jb_dl[k];
            uint4 v = make_uint4(0u, 0u, 0u, 0u);
            if (jb_inb[k] && gd >= 0 && gd < DOUT && (k < 3 || k3act))
                v = *(const uint4*)(xus + (size_t)gd * NPIX + jb_row[k]);
            dat[k] = v;
        }
        __syncthreads(); // previous chunk's readers done
#pragma unroll
        for (int k = 0; k < 4; ++k) {
            if (k < 3 || k3act) {
                int base = jb_lds[k];
                unsigned q;
                q = dat[k].x;
                su[base + 0 * PIXSTRIDE] = __uint_as_float(q << 16);
                su[base + 1 * PIXSTRIDE] = __uint_as_float(q & 0xFFFF0000u);
                q = dat[k].y;
                su[base + 2 * PIXSTRIDE] = __uint_as_float(q << 16);
                su[base + 3 * PIXSTRIDE] = __uint_as_float(q & 0xFFFF0000u);
                q = dat[k].z;
                su[base + 4 * PIXSTRIDE] = __uint_as_float(q << 16);
                su[base + 5 * PIXSTRIDE] = __uint_as_float(q & 0xFFFF0000u);
                q = dat[k].w;
                su[base + 6 * PIXSTRIDE] = __uint_as_float(q << 16);
                su[base + 7 * PIXSTRIDE] = __uint_as_float(q & 0xFFFF0000u);
            }
        }
        __syncthreads();

        float acc[8] = {0.f, 0.f, 0.f, 0.f, 0.f, 0.f, 0.f, 0.f};
#pragma unroll
        for (int i = 0; i < 5; ++i) {
#pragma unroll
            for (int j = 0; j < 5; ++j) {
                const int t = i * 5 + j;
                const float* sp =
                    su + pbase + (i * ROWSTRIDE + j) * PIXSTRIDE;
                float4 va = *(const float4*)sp;
                float4 vb = *(const float4*)(sp + 4);
                float2 vc = *(const float2*)(sp + 8);
                float v[10] = {va.x, va.y, va.z, va.w, vb.x,
                               vb.y, vb.z, vb.w, vc.x, vc.y};
                unsigned q0 = gp[t >> 1], q1 = gp[13 + (t >> 1)],
                         q2 = gp[26 + (t >> 1)];
                float g0 = __uint_as_float((t & 1) ? (q0 & 0xFFFF0000u)
                                                   : (q0 << 16));
                float g1 = __uint_as_float((t & 1) ? (q1 & 0xFFFF0000u)
                                                   : (q1 << 16));
                float g2 = __uint_as_float((t & 1) ? (q2 & 0xFFFF0000u)
                                                   : (q2 << 16));
#pragma unroll
                for (int dd = 0; dd < 8; ++dd)
                    acc[dd] += g1 * v[dd] + g0 * v[dd + 1] + g2 * v[dd + 2];
            }
        }

        if (MODE == 0) {
#pragma unroll
            for (int dd = 0; dd < 8; ++dd) {
                int d = d0 + dd;
                if (d < dend)
                    yout[(size_t)d * NPIX + pix] = __float2bfloat16(acc[dd]);
            }
        } else {
#pragma unroll
            for (int dd = 0; dd < 8; ++dd) {
                int d = d0 + dd;
                if (d < dend) {
                    float v = -acc[dd];
                    float mx = fmaxf(m, v);
                    float sc = __expf(m - mx);
                    float e = __expf(v - mx);
                    l = l * sc + e;
                    s_acc = s_acc * sc + e * (float)d;
                    m = mx;
                }
            }
        }
    }

    if (MODE == 1) {
        float* pz = part + (size_t)blockIdx.z * 3 * NPIX;
        pz[pix] = m;
        pz[NPIX + pix] = l;
        pz[2 * NPIX + pix] = s_acc;
    }
}

// ---------------------------------------------------------------------------
// Kernel 4: merge NZ online-softmin partials per pixel -> disparity.
// ---------------------------------------------------------------------------
__global__ void reduce2_kernel(const float* __restrict__ part,
                               float* __restrict__ out) {
    int pix = blockIdx.x * blockDim.x + threadIdx.x;
    float M = -1e30f, L = 0.f, S = 0.f;
#pragma unroll
    for (int z = 0; z < NZ; ++z) {
        const float* pz = part + (size_t)z * 3 * NPIX;
        float m = pz[pix];
        float l = pz[NPIX + pix];
        float s = pz[2 * NPIX + pix];
        float mx = fmaxf(M, m);
        float a = __expf(M - mx);
        float b = __expf(m - mx);
        L = L * a + l * b;
        S = S * a + s * b;
        M = mx;
    }
    out[pix] = S / L;
}

// ---------------------------------------------------------------------------
extern "C" void kernel_launch(void* const* d_in, const int* in_sizes, int n_in,
                              void* d_out, int out_size, void* d_ws,
                              size_t ws_size, hipStream_t stream) {
    const float* x = (const float*)d_in[0];
    const float* lg1 = (const float*)d_in[1];
    const float* cw = (const float*)d_in[2];
    float* out = (float*)d_out;

    // ws: c fp32 [100352] | u bf16 [NUPS] | y1 bf16 [NUPS].
    // LGA2's (m,l,s) partials overlay u (dead after LGA1).
    float* c = (float*)d_ws;
    __hip_bfloat16* u = (__hip_bfloat16*)((char*)d_ws + (size_t)NCONV * 4);
    __hip_bfloat16* y1 = u + (size_t)NUPS;
    float* part = (float*)u;

    conv3d_kernel<<<(NCONV + 255) / 256, 256, 0, stream>>>(x, cw, c);
    upsample_kernel<<<(DOUT * HOUT * 64 + 255) / 256, 256, 0, stream>>>(c, u);

    dim3 grid(WOUT / 16, HOUT / 16, NZ); // 32 x 16 x 4 = 2048 blocks
    lga_kernel<0><<<grid, 256, 0, stream>>>(u, lg1, y1, nullptr);
    lga_kernel<1><<<grid, 256, 0, stream>>>(y1, lg1, nullptr, part);

    reduce2_kernel<<<NPIX / 256, 256, 0, stream>>>(part, out);
}

// Round 7
// 642.356 us; speedup vs baseline: 8.9902x; 8.9902x over previous
//
#include <hip/hip_runtime.h>
#include <hip/hip_bf16.h>

#define DIN 49
#define HIN 32
#define WIN 64
#define CIN 32
#define DOUT 193
#define HOUT 256
#define WOUT 512
#define NPIX (HOUT * WOUT)      // 131072
#define NUPS (DOUT * NPIX)      // 25296896
#define NCONV (DIN * HIN * WIN) // 100352
#define DSPLIT 64
#define NZ 4 // 3 full z-slices of 64 + 1-plane tail (d=192)

// LGA LDS geometry: d-contiguous per pixel.
#define ROWS 20      // h halo rows
#define ROWSTRIDE 33 // pixel-row stride in pixels
#define PIXSTRIDE 12 // words per pixel (10 planes + 2 pad; 48 B, 16B-aligned)
#define NJOBS 800    // 10 planes * 20 rows * 4 segs
#define SUWORDS 7920

// ---------------------------------------------------------------------------
// Kernel 1: 3x3x3 conv, 32 -> 1 channels, zero pad 1, fp32 accumulate.
// ---------------------------------------------------------------------------
__global__ void conv3d_kernel(const float* __restrict__ x,
                              const float* __restrict__ w,
                              float* __restrict__ c) {
    __shared__ float ws[CIN * 27];
    for (int t = threadIdx.x; t < CIN * 27; t += blockDim.x)
        ws[t] = w[t];
    __syncthreads();

    int idx = blockIdx.x * blockDim.x + threadIdx.x;
    if (idx >= NCONV) return;
    int wq = idx % WIN;
    int t2 = idx / WIN;
    int hq = t2 % HIN;
    int dq = t2 / HIN;

    float acc = 0.f;
    for (int ci = 0; ci < CIN; ++ci) {
        const float* xb = x + ci * NCONV;
        const float* wb = ws + ci * 27;
#pragma unroll
        for (int kd = 0; kd < 3; ++kd) {
            int zd = dq + kd - 1;
            if (zd < 0 || zd >= DIN) continue;
#pragma unroll
            for (int kh = 0; kh < 3; ++kh) {
                int zh = hq + kh - 1;
                if (zh < 0 || zh >= HIN) continue;
#pragma unroll
                for (int kw = 0; kw < 3; ++kw) {
                    int zw = wq + kw - 1;
                    if (zw < 0 || zw >= WIN) continue;
                    acc += xb[(zd * HIN + zh) * WIN + zw] *
                           wb[(kd * 3 + kh) * 3 + kw];
                }
            }
        }
    }
    c[idx] = acc;
}

// ---------------------------------------------------------------------------
// Kernel 2: trilinear upsample, 8 outputs/thread along w, uint4 stores.
// ---------------------------------------------------------------------------
__global__ void upsample_kernel(const float* __restrict__ c,
                                __hip_bfloat16* __restrict__ u) {
    int t = blockIdx.x * blockDim.x + threadIdx.x;
    int wc = t & 63;
    int rest = t >> 6;
    int hh = rest & 255;
    int dd = rest >> 8;
    if (dd >= DOUT) return;

    float fd = (dd + 0.5f) * (49.0f / 193.0f) - 0.5f;
    fd = fminf(fmaxf(fd, 0.f), (float)(DIN - 1));
    int d0 = min((int)fd, DIN - 2);
    float ad = fd - (float)d0;

    float fh = (hh + 0.5f) * 0.125f - 0.5f;
    fh = fminf(fmaxf(fh, 0.f), (float)(HIN - 1));
    int h0 = min((int)fh, HIN - 2);
    float ah = fh - (float)h0;

    int cm1 = max(wc - 1, 0);
    int cp1 = min(wc + 1, WIN - 1);
    const float* p00 = c + (d0 * HIN + h0) * WIN;
    const float* p01 = p00 + WIN;
    const float* p10 = p00 + HIN * WIN;
    const float* p11 = p10 + WIN;

    float a[3];
    {
        float q00, q01, q10, q11;
        q00 = p00[cm1]; q01 = p01[cm1]; q10 = p10[cm1]; q11 = p11[cm1];
        a[0] = (q00 + ah * (q01 - q00)) * (1.f - ad) +
               (q10 + ah * (q11 - q10)) * ad;
        q00 = p00[wc]; q01 = p01[wc]; q10 = p10[wc]; q11 = p11[wc];
        a[1] = (q00 + ah * (q01 - q00)) * (1.f - ad) +
               (q10 + ah * (q11 - q10)) * ad;
        q00 = p00[cp1]; q01 = p01[cp1]; q10 = p10[cp1]; q11 = p11[cp1];
        a[2] = (q00 + ah * (q01 - q00)) * (1.f - ad) +
               (q10 + ah * (q11 - q10)) * ad;
    }

    union {
        unsigned short us[8];
        uint4 v4;
    } pk;
#pragma unroll
    for (int i = 0; i < 8; ++i) {
        float fw = (float)(wc * 8 + i) * 0.125f + (0.0625f - 0.5f);
        fw = fminf(fmaxf(fw, 0.f), (float)(WIN - 1));
        int w0 = min((int)fw, WIN - 2);
        float aw = fw - (float)w0;
        int idx = w0 - (wc - 1);
        float lo = (idx == 0) ? a[0] : a[1];
        float hi = (idx == 0) ? a[1] : a[2];
        float v = lo + aw * (hi - lo);
        __hip_bfloat16 b = __float2bfloat16(v);
        unsigned short usv;
        __builtin_memcpy(&usv, &b, 2);
        pk.us[i] = usv;
    }
    *((uint4*)(u + (size_t)dd * NPIX + hh * WOUT + wc * 8)) = pk.v4;
}

// ---------------------------------------------------------------------------
// LGA: 16x16 pixel tile x DSPLIT d-planes per block. d-contiguous LDS with
// DOUBLE BUFFER -> one barrier per chunk. Loads for chunk k+1 issue right
// after the barrier (latency hidden under chunk-k compute). bf16-packed
// guidance in registers. NO occupancy forcing (rounds 4/6: any forced cap
// spills -> GBs of scratch HBM traffic; true demand ~160-200 VGPR).
// MODE 0: write volume (bf16). MODE 1: per-z online softmin partials.
// ---------------------------------------------------------------------------
__device__ __forceinline__ unsigned short bf16bits(float f) {
    __hip_bfloat16 h = __float2bfloat16(f);
    unsigned short b;
    __builtin_memcpy(&b, &h, 2);
    return b;
}

template <int MODE>
__global__ __launch_bounds__(256) void lga_kernel(
    const __hip_bfloat16* __restrict__ xin,
    const float* __restrict__ lg1,
    __hip_bfloat16* __restrict__ yout,
    float* __restrict__ part) {
    const int tid = threadIdx.x;
    const int tx = tid & 15;
    const int ty = tid >> 4;
    const int w0p = blockIdx.x * 16;
    const int h0p = blockIdx.y * 16;
    const int zb = blockIdx.z * DSPLIT;
    const int dend = min(zb + DSPLIT, DOUT);
    const int pix = (h0p + ty) * WOUT + (w0p + tx);
    const unsigned short* xus = (const unsigned short*)xin;

    __shared__ __align__(16) float su[2][SUWORDS]; // 63.4 KB, double buffer

    // ---- staging job decode (once): j = dl*80 + r*4 + seg (seg fastest) ----
    // k = 0..2 always active; k = 3 active iff tid < 32 (NJOBS = 800).
    int jb_lds[4], jb_row[4], jb_dl[4];
    bool jb_inb[4]; // spatial in-bounds (gh, gw)
#pragma unroll
    for (int k = 0; k < 4; ++k) {
        int j = tid + k * 256;
        int jj = (k == 3 && tid >= 32) ? 0 : j;
        int seg = jj & 3;
        int rowjob = jj >> 2; // dl*20 + r
        int r = rowjob % ROWS;
        int dl = rowjob / ROWS;
        int gh = h0p - 2 + r;
        int gwb = w0p - 8 + seg * 8; // 8-aligned -> 16B-aligned byte addr
        jb_dl[k] = dl;
        jb_lds[k] = (r * ROWSTRIDE + seg * 8) * PIXSTRIDE + dl;
        jb_row[k] = gh * WOUT + gwb;
        jb_inb[k] = gh >= 0 && gh < HOUT && gwb >= 0 && (gwb + 8) <= WOUT;
    }
    const bool k3act = (tid < 32);

    uint4 dat[4];
    auto load_chunk = [&](int d0) {
#pragma unroll
        for (int k = 0; k < 4; ++k) {
            int gd = d0 - 1 + jb_dl[k];
            uint4 v = make_uint4(0u, 0u, 0u, 0u);
            if (jb_inb[k] && gd >= 0 && gd < DOUT && (k < 3 || k3act))
                v = *(const uint4*)(xus + (size_t)gd * NPIX + jb_row[k]);
            dat[k] = v;
        }
    };
    auto write_buf = [&](float* sb) {
#pragma unroll
        for (int k = 0; k < 4; ++k) {
            if (k < 3 || k3act) {
                int base = jb_lds[k];
                unsigned q;
                q = dat[k].x;
                sb[base + 0 * PIXSTRIDE] = __uint_as_float(q << 16);
                sb[base + 1 * PIXSTRIDE] = __uint_as_float(q & 0xFFFF0000u);
                q = dat[k].y;
                sb[base + 2 * PIXSTRIDE] = __uint_as_float(q << 16);
                sb[base + 3 * PIXSTRIDE] = __uint_as_float(q & 0xFFFF0000u);
                q = dat[k].z;
                sb[base + 4 * PIXSTRIDE] = __uint_as_float(q << 16);
                sb[base + 5 * PIXSTRIDE] = __uint_as_float(q & 0xFFFF0000u);
                q = dat[k].w;
                sb[base + 6 * PIXSTRIDE] = __uint_as_float(q << 16);
                sb[base + 7 * PIXSTRIDE] = __uint_as_float(q & 0xFFFF0000u);
            }
        }
    };

    // Prologue: stage chunk 0 into buffer 0 (first loop barrier publishes it).
    load_chunk(zb);

    // ---- guidance: two passes over lg1 to keep register pressure low ----
    float asum = 0.f;
#pragma unroll
    for (int ch = 0; ch < 75; ++ch) asum += fabsf(lg1[ch * NPIX + pix]);
    float inv = 1.f / fmaxf(asum, 1e-12f);
    unsigned gp[39]; // 3 sections x 13 bf16-pairs
#pragma unroll
    for (int s = 0; s < 3; ++s)
#pragma unroll
        for (int p = 0; p < 13; ++p) {
            int c0 = s * 25 + 2 * p;
            float w0 = lg1[c0 * NPIX + pix] * inv;
            float w1 = (2 * p + 1 < 25) ? lg1[(c0 + 1) * NPIX + pix] * inv : 0.f;
            gp[s * 13 + p] =
                (unsigned)bf16bits(w0) | ((unsigned)bf16bits(w1) << 16);
        }

    write_buf(&su[0][0]);

    const int pbase = (ty * ROWSTRIDE + tx + 6) * PIXSTRIDE;
    __hip_bfloat16* ybase = yout + pix;

    float m = -1e30f, l = 0.f, s_acc = 0.f; // MODE 1 online-softmin state
    int cur = 0;

    for (int d0 = zb; d0 < dend; d0 += 8) {
        const bool havenext = (d0 + 8 < dend);
        __syncthreads(); // publishes su[cur]; also WAR-protects su[cur^1]
        if (havenext) load_chunk(d0 + 8); // latency hides under compute

        const float* sc_ = &su[cur][0];
        float acc[8] = {0.f, 0.f, 0.f, 0.f, 0.f, 0.f, 0.f, 0.f};
#pragma unroll
        for (int i = 0; i < 5; ++i) {
#pragma unroll
            for (int j = 0; j < 5; ++j) {
                const int t = i * 5 + j;
                const float* sp = sc_ + pbase + (i * ROWSTRIDE + j) * PIXSTRIDE;
                float4 va = *(const float4*)sp;
                float4 vb = *(const float4*)(sp + 4);
                float2 vc = *(const float2*)(sp + 8);
                unsigned q0 = gp[t >> 1], q1 = gp[13 + (t >> 1)],
                         q2 = gp[26 + (t >> 1)];
                float g0 = __uint_as_float((t & 1) ? (q0 & 0xFFFF0000u)
                                                   : (q0 << 16));
                float g1 = __uint_as_float((t & 1) ? (q1 & 0xFFFF0000u)
                                                   : (q1 << 16));
                float g2 = __uint_as_float((t & 1) ? (q2 & 0xFFFF0000u)
                                                   : (q2 << 16));
                acc[0] += g1 * va.x + g0 * va.y + g2 * va.z;
                acc[1] += g1 * va.y + g0 * va.z + g2 * va.w;
                acc[2] += g1 * va.z + g0 * va.w + g2 * vb.x;
                acc[3] += g1 * va.w + g0 * vb.x + g2 * vb.y;
                acc[4] += g1 * vb.x + g0 * vb.y + g2 * vb.z;
                acc[5] += g1 * vb.y + g0 * vb.z + g2 * vb.w;
                acc[6] += g1 * vb.z + g0 * vb.w + g2 * vc.x;
                acc[7] += g1 * vb.w + g0 * vc.x + g2 * vc.y;
            }
        }

        if (havenext) write_buf(&su[cur ^ 1][0]);
        cur ^= 1;

        if (MODE == 0) {
            if (d0 + 8 <= dend) {
#pragma unroll
                for (int dd = 0; dd < 8; ++dd)
                    ybase[(size_t)(d0 + dd) * NPIX] = __float2bfloat16(acc[dd]);
            } else {
#pragma unroll
                for (int dd = 0; dd < 8; ++dd)
                    if (d0 + dd < dend)
                        ybase[(size_t)(d0 + dd) * NPIX] =
                            __float2bfloat16(acc[dd]);
            }
        } else {
            if (d0 + 8 <= dend) {
                float v0 = -acc[0], v1 = -acc[1], v2 = -acc[2], v3 = -acc[3];
                float v4 = -acc[4], v5 = -acc[5], v6 = -acc[6], v7 = -acc[7];
                float mx = fmaxf(fmaxf(fmaxf(v0, v1), fmaxf(v2, v3)),
                                 fmaxf(fmaxf(v4, v5), fmaxf(v6, v7)));
                mx = fmaxf(mx, m);
                float sc = __expf(m - mx);
                float e0 = __expf(v0 - mx), e1 = __expf(v1 - mx);
                float e2 = __expf(v2 - mx), e3 = __expf(v3 - mx);
                float e4 = __expf(v4 - mx), e5 = __expf(v5 - mx);
                float e6 = __expf(v6 - mx), e7 = __expf(v7 - mx);
                l = l * sc + ((e0 + e1) + (e2 + e3)) + ((e4 + e5) + (e6 + e7));
                float fd0 = (float)d0;
                s_acc = s_acc * sc + e0 * fd0 + e1 * (fd0 + 1.f) +
                        e2 * (fd0 + 2.f) + e3 * (fd0 + 3.f) + e4 * (fd0 + 4.f) +
                        e5 * (fd0 + 5.f) + e6 * (fd0 + 6.f) + e7 * (fd0 + 7.f);
                m = mx;
            } else {
#pragma unroll
                for (int dd = 0; dd < 8; ++dd) {
                    int d = d0 + dd;
                    if (d < dend) {
                        float v = -acc[dd];
                        float mx = fmaxf(m, v);
                        float sc = __expf(m - mx);
                        float e = __expf(v - mx);
                        l = l * sc + e;
                        s_acc = s_acc * sc + e * (float)d;
                        m = mx;
                    }
                }
            }
        }
    }

    if (MODE == 1) {
        float* pz = part + (size_t)blockIdx.z * 3 * NPIX;
        pz[pix] = m;
        pz[NPIX + pix] = l;
        pz[2 * NPIX + pix] = s_acc;
    }
}

// ---------------------------------------------------------------------------
// Kernel 4: merge NZ online-softmin partials per pixel -> disparity.
// ---------------------------------------------------------------------------
__global__ void reduce2_kernel(const float* __restrict__ part,
                               float* __restrict__ out) {
    int pix = blockIdx.x * blockDim.x + threadIdx.x;
    float M = -1e30f, L = 0.f, S = 0.f;
#pragma unroll
    for (int z = 0; z < NZ; ++z) {
        const float* pz = part + (size_t)z * 3 * NPIX;
        float m = pz[pix];
        float l = pz[NPIX + pix];
        float s = pz[2 * NPIX + pix];
        float mx = fmaxf(M, m);
        float a = __expf(M - mx);
        float b = __expf(m - mx);
        L = L * a + l * b;
        S = S * a + s * b;
        M = mx;
    }
    out[pix] = S / L;
}

// ---------------------------------------------------------------------------
extern "C" void kernel_launch(void* const* d_in, const int* in_sizes, int n_in,
                              void* d_out, int out_size, void* d_ws,
                              size_t ws_size, hipStream_t stream) {
    const float* x = (const float*)d_in[0];
    const float* lg1 = (const float*)d_in[1];
    const float* cw = (const float*)d_in[2];
    float* out = (float*)d_out;

    // ws: c fp32 [100352] | u bf16 [NUPS] | y1 bf16 [NUPS].
    // LGA2's (m,l,s) partials overlay u (dead after LGA1).
    float* c = (float*)d_ws;
    __hip_bfloat16* u = (__hip_bfloat16*)((char*)d_ws + (size_t)NCONV * 4);
    __hip_bfloat16* y1 = u + (size_t)NUPS;
    float* part = (float*)u;

    conv3d_kernel<<<(NCONV + 255) / 256, 256, 0, stream>>>(x, cw, c);
    upsample_kernel<<<(DOUT * HOUT * 64 + 255) / 256, 256, 0, stream>>>(c, u);

    dim3 grid(WOUT / 16, HOUT / 16, NZ); // 32 x 16 x 4 = 2048 blocks
    lga_kernel<0><<<grid, 256, 0, stream>>>(u, lg1, y1, nullptr);
    lga_kernel<1><<<grid, 256, 0, stream>>>(y1, lg1, nullptr, part);

    reduce2_kernel<<<NPIX / 256, 256, 0, stream>>>(part, out);
}

// Round 8
// 546.576 us; speedup vs baseline: 10.5656x; 1.1752x over previous
//
#include <hip/hip_runtime.h>
#include <hip/hip_bf16.h>

#define DIN 49
#define HIN 32
#define WIN 64
#define CIN 32
#define DOUT 193
#define HOUT 256
#define WOUT 512
#define NPIX (HOUT * WOUT)      // 131072
#define NUPS (DOUT * NPIX)      // 25296896
#define NCONV (DIN * HIN * WIN) // 100352
#define DSPLIT 64
#define NZ 4 // 3 full z-slices of 64 + 1-plane tail (d=192)

// LGA LDS geometry: d-contiguous per pixel.
#define ROWS 20      // h halo rows
#define ROWSTRIDE 33 // pixel-row stride in pixels
#define PIXSTRIDE 12 // words per pixel (10 planes + 2 pad; 48 B, 16B-aligned)
#define SUWORDS 7920

// ---------------------------------------------------------------------------
// Kernel 1: 3x3x3 conv, 32 -> 1 channels, zero pad 1. Interior fast path.
// ---------------------------------------------------------------------------
__global__ void conv3d_kernel(const float* __restrict__ x,
                              const float* __restrict__ w,
                              float* __restrict__ c) {
    __shared__ float ws[CIN * 27];
    for (int t = threadIdx.x; t < CIN * 27; t += blockDim.x)
        ws[t] = w[t];
    __syncthreads();

    int idx = blockIdx.x * blockDim.x + threadIdx.x;
    if (idx >= NCONV) return;
    int wq = idx % WIN;
    int t2 = idx / WIN;
    int hq = t2 % HIN;
    int dq = t2 / HIN;

    float acc = 0.f;
    if (dq >= 1 && dq < DIN - 1 && hq >= 1 && hq < HIN - 1 && wq >= 1 &&
        wq < WIN - 1) {
        const float* xb = x + ((dq - 1) * HIN + (hq - 1)) * WIN + (wq - 1);
        for (int ci = 0; ci < CIN; ++ci) {
            const float* base = xb + ci * NCONV;
            const float* wb = ws + ci * 27;
#pragma unroll
            for (int kd = 0; kd < 3; ++kd)
#pragma unroll
                for (int kh = 0; kh < 3; ++kh) {
                    const float* row = base + (kd * HIN + kh) * WIN;
                    const float* wr = wb + (kd * 3 + kh) * 3;
                    acc += row[0] * wr[0] + row[1] * wr[1] + row[2] * wr[2];
                }
        }
    } else {
        for (int ci = 0; ci < CIN; ++ci) {
            const float* xb = x + ci * NCONV;
            const float* wb = ws + ci * 27;
#pragma unroll
            for (int kd = 0; kd < 3; ++kd) {
                int zd = dq + kd - 1;
                if (zd < 0 || zd >= DIN) continue;
#pragma unroll
                for (int kh = 0; kh < 3; ++kh) {
                    int zh = hq + kh - 1;
                    if (zh < 0 || zh >= HIN) continue;
#pragma unroll
                    for (int kw = 0; kw < 3; ++kw) {
                        int zw = wq + kw - 1;
                        if (zw < 0 || zw >= WIN) continue;
                        acc += xb[(zd * HIN + zh) * WIN + zw] *
                               wb[(kd * 3 + kh) * 3 + kw];
                    }
                }
            }
        }
    }
    c[idx] = acc;
}

// ---------------------------------------------------------------------------
// Kernel 2: trilinear upsample, 8 outputs/thread along w, uint4 stores.
// ---------------------------------------------------------------------------
__global__ void upsample_kernel(const float* __restrict__ c,
                                __hip_bfloat16* __restrict__ u) {
    int t = blockIdx.x * blockDim.x + threadIdx.x;
    int wc = t & 63;
    int rest = t >> 6;
    int hh = rest & 255;
    int dd = rest >> 8;
    if (dd >= DOUT) return;

    float fd = (dd + 0.5f) * (49.0f / 193.0f) - 0.5f;
    fd = fminf(fmaxf(fd, 0.f), (float)(DIN - 1));
    int d0 = min((int)fd, DIN - 2);
    float ad = fd - (float)d0;

    float fh = (hh + 0.5f) * 0.125f - 0.5f;
    fh = fminf(fmaxf(fh, 0.f), (float)(HIN - 1));
    int h0 = min((int)fh, HIN - 2);
    float ah = fh - (float)h0;

    int cm1 = max(wc - 1, 0);
    int cp1 = min(wc + 1, WIN - 1);
    const float* p00 = c + (d0 * HIN + h0) * WIN;
    const float* p01 = p00 + WIN;
    const float* p10 = p00 + HIN * WIN;
    const float* p11 = p10 + WIN;

    float a[3];
    {
        float q00, q01, q10, q11;
        q00 = p00[cm1]; q01 = p01[cm1]; q10 = p10[cm1]; q11 = p11[cm1];
        a[0] = (q00 + ah * (q01 - q00)) * (1.f - ad) +
               (q10 + ah * (q11 - q10)) * ad;
        q00 = p00[wc]; q01 = p01[wc]; q10 = p10[wc]; q11 = p11[wc];
        a[1] = (q00 + ah * (q01 - q00)) * (1.f - ad) +
               (q10 + ah * (q11 - q10)) * ad;
        q00 = p00[cp1]; q01 = p01[cp1]; q10 = p10[cp1]; q11 = p11[cp1];
        a[2] = (q00 + ah * (q01 - q00)) * (1.f - ad) +
               (q10 + ah * (q11 - q10)) * ad;
    }

    union {
        unsigned short us[8];
        uint4 v4;
    } pk;
#pragma unroll
    for (int i = 0; i < 8; ++i) {
        float fw = (float)(wc * 8 + i) * 0.125f + (0.0625f - 0.5f);
        fw = fminf(fmaxf(fw, 0.f), (float)(WIN - 1));
        int w0 = min((int)fw, WIN - 2);
        float aw = fw - (float)w0;
        int idx = w0 - (wc - 1);
        float lo = (idx == 0) ? a[0] : a[1];
        float hi = (idx == 0) ? a[1] : a[2];
        float v = lo + aw * (hi - lo);
        __hip_bfloat16 b = __float2bfloat16(v);
        unsigned short usv;
        __builtin_memcpy(&usv, &b, 2);
        pk.us[i] = usv;
    }
    *((uint4*)(u + (size_t)dd * NPIX + hh * WOUT + wc * 8)) = pk.v4;
}

// ---------------------------------------------------------------------------
// LGA: 16x16 pixel tile x DSPLIT d-planes per block. Single-buffer LDS
// (round-5 ordering: load -> barrier -> write -> barrier -> compute).
// Register diet for 3 waves/SIMD (target VGPR <= 168):
//  - guidance loaded ONCE (un-normalized, bf16-packed into 38 regs);
//    normalization applied to acc at the end (LGA is linear in g)
//  - staging metadata recomputed per chunk (no jb arrays)
// NO forced occupancy (rounds 4/6: forcing -> spill -> GBs of scratch).
// MODE 0: write volume (bf16). MODE 1: per-z online softmin partials.
// ---------------------------------------------------------------------------
__device__ __forceinline__ unsigned short bf16bits(float f) {
    __hip_bfloat16 h = __float2bfloat16(f);
    unsigned short b;
    __builtin_memcpy(&b, &h, 2);
    return b;
}

template <int MODE>
__global__ __launch_bounds__(256) void lga_kernel(
    const __hip_bfloat16* __restrict__ xin,
    const float* __restrict__ lg1,
    __hip_bfloat16* __restrict__ yout,
    float* __restrict__ part) {
    const int tid = threadIdx.x;
    const int tx = tid & 15;
    const int ty = tid >> 4;
    const int w0p = blockIdx.x * 16;
    const int h0p = blockIdx.y * 16;
    const int zb = blockIdx.z * DSPLIT;
    const int dend = min(zb + DSPLIT, DOUT);
    const int pix = (h0p + ty) * WOUT + (w0p + tx);
    const unsigned short* xus = (const unsigned short*)xin;

    __shared__ __align__(16) float su[SUWORDS];

    // ---- guidance: single pass, un-normalized, bf16 pairs (38 regs) ----
    float asum = 0.f;
    unsigned gp[38];
#pragma unroll
    for (int p = 0; p < 38; ++p) {
        int c0 = 2 * p, c1 = 2 * p + 1;
        float w0 = lg1[c0 * NPIX + pix];
        float w1 = (c1 < 75) ? lg1[c1 * NPIX + pix] : 0.f;
        unsigned b0 = bf16bits(w0), b1 = bf16bits(w1);
        asum += fabsf(__uint_as_float(b0 << 16)) +
                fabsf(__uint_as_float(b1 << 16));
        gp[p] = b0 | (b1 << 16);
    }
    const float inv = 1.f / fmaxf(asum, 1e-12f);

// weight #idx (0..74), idx compile-time
#define GW(idx)                                              \
    __uint_as_float(((idx) & 1) ? (gp[(idx) >> 1] & 0xFFFF0000u) \
                                : (gp[(idx) >> 1] << 16))

    const int pbase = (ty * ROWSTRIDE + tx + 6) * PIXSTRIDE;
    __hip_bfloat16* ybase = yout + pix;

    float m = -1e30f, l = 0.f, s_acc = 0.f; // MODE 1 online-softmin state

    for (int d0 = zb; d0 < dend; d0 += 8) {
        // ---- staging: decode jobs + issue loads (recomputed, no arrays) ----
        uint4 dat[4];
        int lbase[4];
#pragma unroll
        for (int k = 0; k < 4; ++k) {
            const bool a = (k < 3) || (tid < 32); // NJOBS = 800
            int j = tid + k * 256;
            int seg = j & 3;
            int rowjob = j >> 2;
            int dl = rowjob / 20;
            int r = rowjob - dl * 20;
            int gh = h0p - 2 + r;
            int gwb = w0p - 8 + seg * 8;
            int gd = d0 - 1 + dl;
            lbase[k] = (r * ROWSTRIDE + seg * 8) * PIXSTRIDE + dl;
            uint4 v = make_uint4(0u, 0u, 0u, 0u);
            if (a && gd >= 0 && gd < DOUT && gh >= 0 && gh < HOUT &&
                gwb >= 0 && (gwb + 8) <= WOUT)
                v = *(const uint4*)(xus + (size_t)gd * NPIX + gh * WOUT + gwb);
            dat[k] = v;
        }
        __syncthreads(); // previous chunk's readers done
#pragma unroll
        for (int k = 0; k < 4; ++k) {
            if (k < 3 || tid < 32) {
                int base = lbase[k];
                unsigned q;
                q = dat[k].x;
                su[base + 0 * PIXSTRIDE] = __uint_as_float(q << 16);
                su[base + 1 * PIXSTRIDE] = __uint_as_float(q & 0xFFFF0000u);
                q = dat[k].y;
                su[base + 2 * PIXSTRIDE] = __uint_as_float(q << 16);
                su[base + 3 * PIXSTRIDE] = __uint_as_float(q & 0xFFFF0000u);
                q = dat[k].z;
                su[base + 4 * PIXSTRIDE] = __uint_as_float(q << 16);
                su[base + 5 * PIXSTRIDE] = __uint_as_float(q & 0xFFFF0000u);
                q = dat[k].w;
                su[base + 6 * PIXSTRIDE] = __uint_as_float(q << 16);
                su[base + 7 * PIXSTRIDE] = __uint_as_float(q & 0xFFFF0000u);
            }
        }
        __syncthreads();

        float acc[8] = {0.f, 0.f, 0.f, 0.f, 0.f, 0.f, 0.f, 0.f};
#pragma unroll
        for (int i = 0; i < 5; ++i) {
#pragma unroll
            for (int j = 0; j < 5; ++j) {
                const int t = i * 5 + j;
                const float* sp = su + pbase + (i * ROWSTRIDE + j) * PIXSTRIDE;
                float4 va = *(const float4*)sp;
                float4 vb = *(const float4*)(sp + 4);
                float2 vc = *(const float2*)(sp + 8);
                const float g0 = GW(t);
                const float g1 = GW(25 + t);
                const float g2 = GW(50 + t);
                acc[0] += g1 * va.x + g0 * va.y + g2 * va.z;
                acc[1] += g1 * va.y + g0 * va.z + g2 * va.w;
                acc[2] += g1 * va.z + g0 * va.w + g2 * vb.x;
                acc[3] += g1 * va.w + g0 * vb.x + g2 * vb.y;
                acc[4] += g1 * vb.x + g0 * vb.y + g2 * vb.z;
                acc[5] += g1 * vb.y + g0 * vb.z + g2 * vb.w;
                acc[6] += g1 * vb.z + g0 * vb.w + g2 * vc.x;
                acc[7] += g1 * vb.w + g0 * vc.x + g2 * vc.y;
            }
        }

        if (MODE == 0) {
            if (d0 + 8 <= dend) {
#pragma unroll
                for (int dd = 0; dd < 8; ++dd)
                    ybase[(size_t)(d0 + dd) * NPIX] =
                        __float2bfloat16(acc[dd] * inv);
            } else {
#pragma unroll
                for (int dd = 0; dd < 8; ++dd)
                    if (d0 + dd < dend)
                        ybase[(size_t)(d0 + dd) * NPIX] =
                            __float2bfloat16(acc[dd] * inv);
            }
        } else {
            if (d0 + 8 <= dend) {
                float v0 = -acc[0] * inv, v1 = -acc[1] * inv;
                float v2 = -acc[2] * inv, v3 = -acc[3] * inv;
                float v4 = -acc[4] * inv, v5 = -acc[5] * inv;
                float v6 = -acc[6] * inv, v7 = -acc[7] * inv;
                float mx = fmaxf(fmaxf(fmaxf(v0, v1), fmaxf(v2, v3)),
                                 fmaxf(fmaxf(v4, v5), fmaxf(v6, v7)));
                mx = fmaxf(mx, m);
                float sc = __expf(m - mx);
                float e0 = __expf(v0 - mx), e1 = __expf(v1 - mx);
                float e2 = __expf(v2 - mx), e3 = __expf(v3 - mx);
                float e4 = __expf(v4 - mx), e5 = __expf(v5 - mx);
                float e6 = __expf(v6 - mx), e7 = __expf(v7 - mx);
                l = l * sc + ((e0 + e1) + (e2 + e3)) + ((e4 + e5) + (e6 + e7));
                float fd0 = (float)d0;
                s_acc = s_acc * sc + e0 * fd0 + e1 * (fd0 + 1.f) +
                        e2 * (fd0 + 2.f) + e3 * (fd0 + 3.f) + e4 * (fd0 + 4.f) +
                        e5 * (fd0 + 5.f) + e6 * (fd0 + 6.f) + e7 * (fd0 + 7.f);
                m = mx;
            } else {
#pragma unroll
                for (int dd = 0; dd < 8; ++dd) {
                    int d = d0 + dd;
                    if (d < dend) {
                        float v = -acc[dd] * inv;
                        float mx = fmaxf(m, v);
                        float sc = __expf(m - mx);
                        float e = __expf(v - mx);
                        l = l * sc + e;
                        s_acc = s_acc * sc + e * (float)d;
                        m = mx;
                    }
                }
            }
        }
    }
#undef GW

    if (MODE == 1) {
        float* pz = part + (size_t)blockIdx.z * 3 * NPIX;
        pz[pix] = m;
        pz[NPIX + pix] = l;
        pz[2 * NPIX + pix] = s_acc;
    }
}

// ---------------------------------------------------------------------------
// Kernel 4: merge NZ online-softmin partials per pixel -> disparity.
// ---------------------------------------------------------------------------
__global__ void reduce2_kernel(const float* __restrict__ part,
                               float* __restrict__ out) {
    int pix = blockIdx.x * blockDim.x + threadIdx.x;
    float M = -1e30f, L = 0.f, S = 0.f;
#pragma unroll
    for (int z = 0; z < NZ; ++z) {
        const float* pz = part + (size_t)z * 3 * NPIX;
        float m = pz[pix];
        float l = pz[NPIX + pix];
        float s = pz[2 * NPIX + pix];
        float mx = fmaxf(M, m);
        float a = __expf(M - mx);
        float b = __expf(m - mx);
        L = L * a + l * b;
        S = S * a + s * b;
        M = mx;
    }
    out[pix] = S / L;
}

// ---------------------------------------------------------------------------
extern "C" void kernel_launch(void* const* d_in, const int* in_sizes, int n_in,
                              void* d_out, int out_size, void* d_ws,
                              size_t ws_size, hipStream_t stream) {
    const float* x = (const float*)d_in[0];
    const float* lg1 = (const float*)d_in[1];
    const float* cw = (const float*)d_in[2];
    float* out = (float*)d_out;

    // ws: c fp32 [100352] | u bf16 [NUPS] | y1 bf16 [NUPS].
    // LGA2's (m,l,s) partials overlay u (dead after LGA1).
    float* c = (float*)d_ws;
    __hip_bfloat16* u = (__hip_bfloat16*)((char*)d_ws + (size_t)NCONV * 4);
    __hip_bfloat16* y1 = u + (size_t)NUPS;
    float* part = (float*)u;

    conv3d_kernel<<<(NCONV + 255) / 256, 256, 0, stream>>>(x, cw, c);
    upsample_kernel<<<(DOUT * HOUT * 64 + 255) / 256, 256, 0, stream>>>(c, u);

    dim3 grid(WOUT / 16, HOUT / 16, NZ); // 32 x 16 x 4 = 2048 blocks
    lga_kernel<0><<<grid, 256, 0, stream>>>(u, lg1, y1, nullptr);
    lga_kernel<1><<<grid, 256, 0, stream>>>(y1, lg1, nullptr, part);

    reduce2_kernel<<<NPIX / 256, 256, 0, stream>>>(part, out);
}

// Round 9
// 402.616 us; speedup vs baseline: 14.3434x; 1.3576x over previous
//
#include <hip/hip_runtime.h>
#include <hip/hip_bf16.h>

#define DIN 49
#define HIN 32
#define WIN 64
#define CIN 32
#define DOUT 193
#define HOUT 256
#define WOUT 512
#define NPIX (HOUT * WOUT)      // 131072
#define NUPS (DOUT * NPIX)      // 25296896
#define NCONV (DIN * HIN * WIN) // 100352
#define DSPLIT 64
#define NZ 4 // 3 full z-slices of 64 + 1-plane tail (d=192)
#define CGRP 8 // conv channel groups (4 ci each)

// LGA LDS geometry: d-contiguous per pixel.
#define ROWS 20      // h halo rows
#define ROWSTRIDE 33 // pixel-row stride in pixels
#define PIXSTRIDE 12 // words per pixel (10 planes + 2 pad; 48 B, 16B-aligned)
#define SUWORDS 7920

// ---------------------------------------------------------------------------
// Kernel 1: 3x3x3 conv, 32 -> 1 ch, zero pad 1, split 8 ways over channels.
// Round-8 post-mortem: monolithic version was latency-bound at 392 blocks
// (VALUBusy 5%, 200 us). 4-ci groups -> 3136 blocks, 8x shorter chains.
// ---------------------------------------------------------------------------
__global__ void conv3d_kernel(const float* __restrict__ x,
                              const float* __restrict__ w,
                              float* __restrict__ partial) {
    __shared__ float ws[4 * 27];
    const int grp = blockIdx.y;
    for (int t = threadIdx.x; t < 4 * 27; t += blockDim.x)
        ws[t] = w[grp * (4 * 27) + t];
    __syncthreads();

    int idx = blockIdx.x * blockDim.x + threadIdx.x; // NCONV = 392*256 exact
    int wq = idx % WIN;
    int t2 = idx / WIN;
    int hq = t2 % HIN;
    int dq = t2 / HIN;

    float acc = 0.f;
    const float* xg = x + (size_t)grp * 4 * NCONV;
#pragma unroll
    for (int cl = 0; cl < 4; ++cl) {
        const float* xb = xg + cl * NCONV;
        const float* wb = ws + cl * 27;
#pragma unroll
        for (int kd = 0; kd < 3; ++kd) {
            int zd = dq + kd - 1;
            if (zd < 0 || zd >= DIN) continue;
#pragma unroll
            for (int kh = 0; kh < 3; ++kh) {
                int zh = hq + kh - 1;
                if (zh < 0 || zh >= HIN) continue;
#pragma unroll
                for (int kw = 0; kw < 3; ++kw) {
                    int zw = wq + kw - 1;
                    if (zw < 0 || zw >= WIN) continue;
                    acc += xb[(zd * HIN + zh) * WIN + zw] *
                           wb[(kd * 3 + kh) * 3 + kw];
                }
            }
        }
    }
    partial[(size_t)grp * NCONV + idx] = acc;
}

// ---------------------------------------------------------------------------
// Kernel 1b: fold 8 conv partials -> c.
// ---------------------------------------------------------------------------
__global__ void convfold_kernel(const float* __restrict__ partial,
                                float* __restrict__ c) {
    int idx = blockIdx.x * blockDim.x + threadIdx.x;
    float s = 0.f;
#pragma unroll
    for (int g = 0; g < CGRP; ++g) s += partial[(size_t)g * NCONV + idx];
    c[idx] = s;
}

// ---------------------------------------------------------------------------
// Kernel 2: trilinear upsample, 8 outputs/thread along w, uint4 stores.
// ---------------------------------------------------------------------------
__global__ void upsample_kernel(const float* __restrict__ c,
                                __hip_bfloat16* __restrict__ u) {
    int t = blockIdx.x * blockDim.x + threadIdx.x;
    int wc = t & 63;
    int rest = t >> 6;
    int hh = rest & 255;
    int dd = rest >> 8;
    if (dd >= DOUT) return;

    float fd = (dd + 0.5f) * (49.0f / 193.0f) - 0.5f;
    fd = fminf(fmaxf(fd, 0.f), (float)(DIN - 1));
    int d0 = min((int)fd, DIN - 2);
    float ad = fd - (float)d0;

    float fh = (hh + 0.5f) * 0.125f - 0.5f;
    fh = fminf(fmaxf(fh, 0.f), (float)(HIN - 1));
    int h0 = min((int)fh, HIN - 2);
    float ah = fh - (float)h0;

    int cm1 = max(wc - 1, 0);
    int cp1 = min(wc + 1, WIN - 1);
    const float* p00 = c + (d0 * HIN + h0) * WIN;
    const float* p01 = p00 + WIN;
    const float* p10 = p00 + HIN * WIN;
    const float* p11 = p10 + WIN;

    float a[3];
    {
        float q00, q01, q10, q11;
        q00 = p00[cm1]; q01 = p01[cm1]; q10 = p10[cm1]; q11 = p11[cm1];
        a[0] = (q00 + ah * (q01 - q00)) * (1.f - ad) +
               (q10 + ah * (q11 - q10)) * ad;
        q00 = p00[wc]; q01 = p01[wc]; q10 = p10[wc]; q11 = p11[wc];
        a[1] = (q00 + ah * (q01 - q00)) * (1.f - ad) +
               (q10 + ah * (q11 - q10)) * ad;
        q00 = p00[cp1]; q01 = p01[cp1]; q10 = p10[cp1]; q11 = p11[cp1];
        a[2] = (q00 + ah * (q01 - q00)) * (1.f - ad) +
               (q10 + ah * (q11 - q10)) * ad;
    }

    union {
        unsigned short us[8];
        uint4 v4;
    } pk;
#pragma unroll
    for (int i = 0; i < 8; ++i) {
        float fw = (float)(wc * 8 + i) * 0.125f + (0.0625f - 0.5f);
        fw = fminf(fmaxf(fw, 0.f), (float)(WIN - 1));
        int w0 = min((int)fw, WIN - 2);
        float aw = fw - (float)w0;
        int idx = w0 - (wc - 1);
        float lo = (idx == 0) ? a[0] : a[1];
        float hi = (idx == 0) ? a[1] : a[2];
        float v = lo + aw * (hi - lo);
        __hip_bfloat16 b = __float2bfloat16(v);
        unsigned short usv;
        __builtin_memcpy(&usv, &b, 2);
        pk.us[i] = usv;
    }
    *((uint4*)(u + (size_t)dd * NPIX + hh * WOUT + wc * 8)) = pk.v4;
}

// ---------------------------------------------------------------------------
// LGA: 16x16 pixel tile x DSPLIT d-planes per block. Single-buffer LDS
// (load -> barrier -> write -> barrier -> compute). Register diet keeps
// 3 waves/SIMD (round 8: 546 us total, LGA ~158/pass). UNCHANGED this round.
// NO forced occupancy (rounds 4/6: forcing -> spill -> GBs of scratch).
// MODE 0: write volume (bf16). MODE 1: per-z online softmin partials.
// ---------------------------------------------------------------------------
__device__ __forceinline__ unsigned short bf16bits(float f) {
    __hip_bfloat16 h = __float2bfloat16(f);
    unsigned short b;
    __builtin_memcpy(&b, &h, 2);
    return b;
}

template <int MODE>
__global__ __launch_bounds__(256) void lga_kernel(
    const __hip_bfloat16* __restrict__ xin,
    const float* __restrict__ lg1,
    __hip_bfloat16* __restrict__ yout,
    float* __restrict__ part) {
    const int tid = threadIdx.x;
    const int tx = tid & 15;
    const int ty = tid >> 4;
    const int w0p = blockIdx.x * 16;
    const int h0p = blockIdx.y * 16;
    const int zb = blockIdx.z * DSPLIT;
    const int dend = min(zb + DSPLIT, DOUT);
    const int pix = (h0p + ty) * WOUT + (w0p + tx);
    const unsigned short* xus = (const unsigned short*)xin;

    __shared__ __align__(16) float su[SUWORDS];

    // ---- guidance: single pass, un-normalized, bf16 pairs (38 regs) ----
    float asum = 0.f;
    unsigned gp[38];
#pragma unroll
    for (int p = 0; p < 38; ++p) {
        int c0 = 2 * p, c1 = 2 * p + 1;
        float w0 = lg1[c0 * NPIX + pix];
        float w1 = (c1 < 75) ? lg1[c1 * NPIX + pix] : 0.f;
        unsigned b0 = bf16bits(w0), b1 = bf16bits(w1);
        asum += fabsf(__uint_as_float(b0 << 16)) +
                fabsf(__uint_as_float(b1 << 16));
        gp[p] = b0 | (b1 << 16);
    }
    const float inv = 1.f / fmaxf(asum, 1e-12f);

// weight #idx (0..74), idx compile-time
#define GW(idx)                                              \
    __uint_as_float(((idx) & 1) ? (gp[(idx) >> 1] & 0xFFFF0000u) \
                                : (gp[(idx) >> 1] << 16))

    const int pbase = (ty * ROWSTRIDE + tx + 6) * PIXSTRIDE;
    __hip_bfloat16* ybase = yout + pix;

    float m = -1e30f, l = 0.f, s_acc = 0.f; // MODE 1 online-softmin state

    for (int d0 = zb; d0 < dend; d0 += 8) {
        // ---- staging: decode jobs + issue loads (recomputed, no arrays) ----
        uint4 dat[4];
        int lbase[4];
#pragma unroll
        for (int k = 0; k < 4; ++k) {
            const bool a = (k < 3) || (tid < 32); // NJOBS = 800
            int j = tid + k * 256;
            int seg = j & 3;
            int rowjob = j >> 2;
            int dl = rowjob / 20;
            int r = rowjob - dl * 20;
            int gh = h0p - 2 + r;
            int gwb = w0p - 8 + seg * 8;
            int gd = d0 - 1 + dl;
            lbase[k] = (r * ROWSTRIDE + seg * 8) * PIXSTRIDE + dl;
            uint4 v = make_uint4(0u, 0u, 0u, 0u);
            if (a && gd >= 0 && gd < DOUT && gh >= 0 && gh < HOUT &&
                gwb >= 0 && (gwb + 8) <= WOUT)
                v = *(const uint4*)(xus + (size_t)gd * NPIX + gh * WOUT + gwb);
            dat[k] = v;
        }
        __syncthreads(); // previous chunk's readers done
#pragma unroll
        for (int k = 0; k < 4; ++k) {
            if (k < 3 || tid < 32) {
                int base = lbase[k];
                unsigned q;
                q = dat[k].x;
                su[base + 0 * PIXSTRIDE] = __uint_as_float(q << 16);
                su[base + 1 * PIXSTRIDE] = __uint_as_float(q & 0xFFFF0000u);
                q = dat[k].y;
                su[base + 2 * PIXSTRIDE] = __uint_as_float(q << 16);
                su[base + 3 * PIXSTRIDE] = __uint_as_float(q & 0xFFFF0000u);
                q = dat[k].z;
                su[base + 4 * PIXSTRIDE] = __uint_as_float(q << 16);
                su[base + 5 * PIXSTRIDE] = __uint_as_float(q & 0xFFFF0000u);
                q = dat[k].w;
                su[base + 6 * PIXSTRIDE] = __uint_as_float(q << 16);
                su[base + 7 * PIXSTRIDE] = __uint_as_float(q & 0xFFFF0000u);
            }
        }
        __syncthreads();

        float acc[8] = {0.f, 0.f, 0.f, 0.f, 0.f, 0.f, 0.f, 0.f};
#pragma unroll
        for (int i = 0; i < 5; ++i) {
#pragma unroll
            for (int j = 0; j < 5; ++j) {
                const int t = i * 5 + j;
                const float* sp = su + pbase + (i * ROWSTRIDE + j) * PIXSTRIDE;
                float4 va = *(const float4*)sp;
                float4 vb = *(const float4*)(sp + 4);
                float2 vc = *(const float2*)(sp + 8);
                const float g0 = GW(t);
                const float g1 = GW(25 + t);
                const float g2 = GW(50 + t);
                acc[0] += g1 * va.x + g0 * va.y + g2 * va.z;
                acc[1] += g1 * va.y + g0 * va.z + g2 * va.w;
                acc[2] += g1 * va.z + g0 * va.w + g2 * vb.x;
                acc[3] += g1 * va.w + g0 * vb.x + g2 * vb.y;
                acc[4] += g1 * vb.x + g0 * vb.y + g2 * vb.z;
                acc[5] += g1 * vb.y + g0 * vb.z + g2 * vb.w;
                acc[6] += g1 * vb.z + g0 * vb.w + g2 * vc.x;
                acc[7] += g1 * vb.w + g0 * vc.x + g2 * vc.y;
            }
        }

        if (MODE == 0) {
            if (d0 + 8 <= dend) {
#pragma unroll
                for (int dd = 0; dd < 8; ++dd)
                    ybase[(size_t)(d0 + dd) * NPIX] =
                        __float2bfloat16(acc[dd] * inv);
            } else {
#pragma unroll
                for (int dd = 0; dd < 8; ++dd)
                    if (d0 + dd < dend)
                        ybase[(size_t)(d0 + dd) * NPIX] =
                            __float2bfloat16(acc[dd] * inv);
            }
        } else {
            if (d0 + 8 <= dend) {
                float v0 = -acc[0] * inv, v1 = -acc[1] * inv;
                float v2 = -acc[2] * inv, v3 = -acc[3] * inv;
                float v4 = -acc[4] * inv, v5 = -acc[5] * inv;
                float v6 = -acc[6] * inv, v7 = -acc[7] * inv;
                float mx = fmaxf(fmaxf(fmaxf(v0, v1), fmaxf(v2, v3)),
                                 fmaxf(fmaxf(v4, v5), fmaxf(v6, v7)));
                mx = fmaxf(mx, m);
                float sc = __expf(m - mx);
                float e0 = __expf(v0 - mx), e1 = __expf(v1 - mx);
                float e2 = __expf(v2 - mx), e3 = __expf(v3 - mx);
                float e4 = __expf(v4 - mx), e5 = __expf(v5 - mx);
                float e6 = __expf(v6 - mx), e7 = __expf(v7 - mx);
                l = l * sc + ((e0 + e1) + (e2 + e3)) + ((e4 + e5) + (e6 + e7));
                float fd0 = (float)d0;
                s_acc = s_acc * sc + e0 * fd0 + e1 * (fd0 + 1.f) +
                        e2 * (fd0 + 2.f) + e3 * (fd0 + 3.f) + e4 * (fd0 + 4.f) +
                        e5 * (fd0 + 5.f) + e6 * (fd0 + 6.f) + e7 * (fd0 + 7.f);
                m = mx;
            } else {
#pragma unroll
                for (int dd = 0; dd < 8; ++dd) {
                    int d = d0 + dd;
                    if (d < dend) {
                        float v = -acc[dd] * inv;
                        float mx = fmaxf(m, v);
                        float sc = __expf(m - mx);
                        float e = __expf(v - mx);
                        l = l * sc + e;
                        s_acc = s_acc * sc + e * (float)d;
                        m = mx;
                    }
                }
            }
        }
    }
#undef GW

    if (MODE == 1) {
        float* pz = part + (size_t)blockIdx.z * 3 * NPIX;
        pz[pix] = m;
        pz[NPIX + pix] = l;
        pz[2 * NPIX + pix] = s_acc;
    }
}

// ---------------------------------------------------------------------------
// Kernel 4: merge NZ online-softmin partials per pixel -> disparity.
// ---------------------------------------------------------------------------
__global__ void reduce2_kernel(const float* __restrict__ part,
                               float* __restrict__ out) {
    int pix = blockIdx.x * blockDim.x + threadIdx.x;
    float M = -1e30f, L = 0.f, S = 0.f;
#pragma unroll
    for (int z = 0; z < NZ; ++z) {
        const float* pz = part + (size_t)z * 3 * NPIX;
        float m = pz[pix];
        float l = pz[NPIX + pix];
        float s = pz[2 * NPIX + pix];
        float mx = fmaxf(M, m);
        float a = __expf(M - mx);
        float b = __expf(m - mx);
        L = L * a + l * b;
        S = S * a + s * b;
        M = mx;
    }
    out[pix] = S / L;
}

// ---------------------------------------------------------------------------
extern "C" void kernel_launch(void* const* d_in, const int* in_sizes, int n_in,
                              void* d_out, int out_size, void* d_ws,
                              size_t ws_size, hipStream_t stream) {
    const float* x = (const float*)d_in[0];
    const float* lg1 = (const float*)d_in[1];
    const float* cw = (const float*)d_in[2];
    float* out = (float*)d_out;

    // ws: c fp32 [100352] | u bf16 [NUPS] | y1 bf16 [NUPS].
    // conv partials [8][NCONV] overlay y1 (dead until LGA1, after fold).
    // LGA2's (m,l,s) partials overlay u (dead after LGA1).
    float* c = (float*)d_ws;
    __hip_bfloat16* u = (__hip_bfloat16*)((char*)d_ws + (size_t)NCONV * 4);
    __hip_bfloat16* y1 = u + (size_t)NUPS;
    float* cpart = (float*)y1;
    float* part = (float*)u;

    dim3 cgrid(NCONV / 256, CGRP);
    conv3d_kernel<<<cgrid, 256, 0, stream>>>(x, cw, cpart);
    convfold_kernel<<<NCONV / 256, 256, 0, stream>>>(cpart, c);
    upsample_kernel<<<(DOUT * HOUT * 64 + 255) / 256, 256, 0, stream>>>(c, u);

    dim3 grid(WOUT / 16, HOUT / 16, NZ); // 32 x 16 x 4 = 2048 blocks
    lga_kernel<0><<<grid, 256, 0, stream>>>(u, lg1, y1, nullptr);
    lga_kernel<1><<<grid, 256, 0, stream>>>(y1, lg1, nullptr, part);

    reduce2_kernel<<<NPIX / 256, 256, 0, stream>>>(part, out);
}